// Round 4
// baseline (198.482 us; speedup 1.0000x reference)
//
#include <hip/hip_runtime.h>
#include <stdint.h>

// x: (8,128,16,16) f32 ; codebook: (4,4096,32) f32 ; temperature: (4,1,1,1)
// row = (n*4+m)*256 + hw, 8192 rows, K=4096, D=32
// outputs (flat f32): sample[33554432] code[8192] one_hot[33554432] logit[33554432]

__device__ __forceinline__ uint32_t rotl32(uint32_t x, uint32_t r){
  return (x << r) | (x >> (32u - r));
}

// JAX threefry2x32, key (0,42), partitionable scheme: bits = o0^o1 of
// threefry((0,42),(0,e)); u = bitcast((bits>>9)|0x3F800000)-1, clip, g=-log(-log(u)).
// VALIDATED bit-exact vs reference in Round 2 — do not modify.
__device__ __forceinline__ float gumbel_from_e(uint32_t e){
  uint32_t x0 = 0u, x1 = e;
  const uint32_t ks0 = 0u, ks1 = 42u, ks2 = 0x1BD11BF0u;
  x0 += ks0; x1 += ks1;
#define TFR4(a,b,c,d2) \
  x0 += x1; x1 = rotl32(x1,(a)); x1 ^= x0; \
  x0 += x1; x1 = rotl32(x1,(b)); x1 ^= x0; \
  x0 += x1; x1 = rotl32(x1,(c)); x1 ^= x0; \
  x0 += x1; x1 = rotl32(x1,(d2)); x1 ^= x0;
  TFR4(13,15,26,6)  x0 += ks1; x1 += ks2 + 1u;
  TFR4(17,29,16,24) x0 += ks2; x1 += ks0 + 2u;
  TFR4(13,15,26,6)  x0 += ks0; x1 += ks1 + 3u;
  TFR4(17,29,16,24) x0 += ks1; x1 += ks2 + 4u;
  TFR4(13,15,26,6)  x0 += ks2; x1 += ks0 + 5u;
#undef TFR4
  uint32_t bits = x0 ^ x1;
  float u = __uint_as_float((bits >> 9) | 0x3F800000u) - 1.0f;
  u = fminf(fmaxf(u, 1.1920929e-07f), __uint_as_float(0x3F7FFFFEu));
  return -logf(-logf(u));
}

// Fused kernel: grid 512 = m(4) x rowtile(128 = n(8) x hwtile(16)).
// Block: 512 threads, owns 16 rows x all 4096 k. Loops 16 codebook k-tiles
// through LDS; running argmax (logit and logit+gumbel) in registers; one
// final block reduction; same block zero-fills + scatters sample/one_hot.
__global__ __launch_bounds__(512, 4) void k_fused(
    const float* __restrict__ x, const float* __restrict__ cb,
    const float* __restrict__ temp, float* __restrict__ logit_out,
    float* __restrict__ sample, float* __restrict__ code_out,
    float* __restrict__ onehot){
  __shared__ float cl[9216];      // 256 k x 32 d, stride 36 (b128 reads at 8-way = floor)
  __shared__ float xl[16][36];    // 16 rows x 32 d
  __shared__ float c2l[256];
  __shared__ float x2l[16];
  __shared__ int sHard[16], sCode[16];

  const int tid = threadIdx.x;
  const int b = blockIdx.x;
  const int m   = b >> 7;          // 0..3
  const int rt  = b & 127;
  const int n   = rt >> 4;         // 0..7
  const int hw0 = (rt & 15) << 4;  // 16 consecutive hw
  const int rowbase = ((n << 2) + m) * 256 + hw0;

  // ---- stage x tile (16 rows x 32 d) ----
  {
    const float* xm = x + ((n * 128 + m * 32) * 256 + hw0);
    int d = tid >> 4, r = tid & 15;
    xl[r][d] = xm[(d << 8) + r];
  }
  __syncthreads();
  if (tid < 16){
    float s = 0.f;
    #pragma unroll
    for (int d = 0; d < 32; ++d){ float v = xl[tid][d]; s = fmaf(v, v, s); }
    x2l[tid] = s;
  }
  // x2l visibility for kt=0 is covered by the pre-stage barrier below.

  const float tcl = fmaxf(temp[m], 1e-6f);
  const int kg = tid & 63;         // k within group; ks = k0 + kg + 64*j
  const int rg = tid >> 6;         // wave-uniform row group; rows 2*rg, 2*rg+1

  float bl[2], bg[2]; int bli[2], bgi[2];
  #pragma unroll
  for (int i = 0; i < 2; ++i){ bl[i] = -INFINITY; bg[i] = -INFINITY; bli[i] = 0; bgi[i] = 0; }

  const float4* cbm = (const float4*)(cb + (size_t)m * 131072);

  for (int kt = 0; kt < 16; ++kt){
    const int k0 = kt << 8;
    __syncthreads();               // previous tile's cl/c2l reads done
    // ---- stage codebook tile (256 k x 32 d), coalesced float4 ----
    #pragma unroll
    for (int i2 = 0; i2 < 4; ++i2){
      int f = tid + (i2 << 9);
      float4 v = cbm[(k0 << 3) + f];       // k0*32/4
      int kk = f >> 3, dq = f & 7;
      *(float4*)&cl[kk * 36 + (dq << 2)] = v;
    }
    __syncthreads();
    if (tid < 256){
      float s = 0.f;
      #pragma unroll
      for (int d = 0; d < 32; ++d){ float c = cl[tid*36 + d]; s = fmaf(c, c, s); }
      c2l[tid] = s;
    }
    __syncthreads();

    // ---- GEMM: 2 rows x 4 ks per thread ----
    float acc[2][4];
    #pragma unroll
    for (int i = 0; i < 2; ++i)
      #pragma unroll
      for (int j = 0; j < 4; ++j) acc[i][j] = 0.f;

    #pragma unroll
    for (int dblk = 0; dblk < 8; ++dblk){
      float4 xa[2];
      xa[0] = *(const float4*)&xl[(rg << 1) + 0][dblk << 2];  // broadcast (rg wave-uniform)
      xa[1] = *(const float4*)&xl[(rg << 1) + 1][dblk << 2];
      #pragma unroll
      for (int j = 0; j < 4; ++j){
        float4 cv = *(const float4*)&cl[(kg + (j << 6)) * 36 + (dblk << 2)];
        #pragma unroll
        for (int i = 0; i < 2; ++i){
          acc[i][j] = fmaf(xa[i].x, cv.x, acc[i][j]);
          acc[i][j] = fmaf(xa[i].y, cv.y, acc[i][j]);
          acc[i][j] = fmaf(xa[i].z, cv.z, acc[i][j]);
          acc[i][j] = fmaf(xa[i].w, cv.w, acc[i][j]);
        }
      }
    }

    // ---- logits + gumbel + running argmax (k ascending per thread) ----
    #pragma unroll
    for (int j = 0; j < 4; ++j){
      const int kk = kg + (j << 6);
      const int k_g = k0 + kk;
      const float c2 = c2l[kk];
      #pragma unroll
      for (int i = 0; i < 2; ++i){
        const int r = (rg << 1) + i;
        const int row_g = rowbase + r;
        float dist = x2l[r] + c2 - 2.0f * acc[i][j];
        float l = (-dist) * 0.015625f * tcl;      // (-dist/64)*t
        logit_out[((size_t)row_g << 12) + k_g] = l;
        float lg = l + gumbel_from_e(((uint32_t)row_g << 12) + (uint32_t)k_g);
        if (l  > bl[i]) { bl[i] = l;  bli[i] = k_g; }
        if (lg > bg[i]) { bg[i] = lg; bgi[i] = k_g; }
      }
    }
  }

  // ---- single final block reduction over the 64 k-groups (reuse cl) ----
  __syncthreads();
  float* red = cl;                 // 4 arrays of 16*65
  #pragma unroll
  for (int i = 0; i < 2; ++i){
    int r = (rg << 1) + i;
    red[        r * 65 + kg] = bl[i];
    red[1040 +  r * 65 + kg] = __int_as_float(bli[i]);
    red[2080 +  r * 65 + kg] = bg[i];
    red[3120 +  r * 65 + kg] = __int_as_float(bgi[i]);
  }
  __syncthreads();
  if (tid < 32){
    const int r = tid & 15;
    const bool doG = (tid >= 16);
    const int off_v = doG ? 2080 : 0;
    const int off_i = doG ? 3120 : 1040;
    float bv = -INFINITY; int bi = 0;
    for (int g = 0; g < 64; ++g){
      float v = red[off_v + r * 65 + g];
      int  ix = __float_as_int(red[off_i + r * 65 + g]);
      if (v > bv || (v == bv && ix < bi)){ bv = v; bi = ix; }
    }
    if (doG) sHard[r] = bi;
    else { sCode[r] = bi; code_out[rowbase + r] = (float)bi; }
  }
  __syncthreads();

  // ---- zero-fill + fused scatter: 16 rows x 1024 float4 per output ----
  float4* s4 = (float4*)(sample + ((size_t)rowbase << 12));
  float4* o4 = (float4*)(onehot + ((size_t)rowbase << 12));
  #pragma unroll
  for (int i = 0; i < 32; ++i){
    int idx = tid + (i << 9);
    int r = idx >> 10;
    int w = idx & 1023;                        // float4 slot within row
    int h = sHard[r], c = sCode[r];
    float4 vs = make_float4(0.f, 0.f, 0.f, 0.f);
    float4 vo = make_float4(0.f, 0.f, 0.f, 0.f);
    if ((h >> 2) == w) ((float*)&vs)[h & 3] = 1.0f;  // sample = y_hard exactly
    if ((c >> 2) == w) ((float*)&vo)[c & 3] = 1.0f;  // one_hot(argmax(logit))
    s4[idx] = vs;
    o4[idx] = vo;
  }
}

extern "C" void kernel_launch(void* const* d_in, const int* in_sizes, int n_in,
                              void* d_out, int out_size, void* d_ws, size_t ws_size,
                              hipStream_t stream) {
  const float* x    = (const float*)d_in[0];
  const float* cb   = (const float*)d_in[1];
  const float* temp = (const float*)d_in[2];
  float* out    = (float*)d_out;
  float* sample = out;                       // 33554432
  float* code   = out + 33554432;            // 8192
  float* onehot = code + 8192;               // 33554432
  float* logit  = onehot + 33554432;         // 33554432

  hipLaunchKernelGGL(k_fused, dim3(512), dim3(512), 0, stream,
                     x, cb, temp, logit, sample, code, onehot);
}

// Round 6
// 145.601 us; speedup vs baseline: 1.3632x; 1.3632x over previous
//
#include <hip/hip_runtime.h>
#include <stdint.h>

// x: (8,128,16,16) f32 ; codebook: (4,4096,32) f32 ; temperature: (4,1,1,1)
// row = (n*4+m)*256 + hw, 8192 rows, K=4096, D=32
// outputs (flat f32): sample[33554432] code[8192] one_hot[33554432] logit[33554432]

__device__ __forceinline__ uint32_t rotl32(uint32_t x, uint32_t r){
  return (x << r) | (x >> (32u - r));
}

// JAX threefry2x32, key (0,42), partitionable scheme: bits = o0^o1 of
// threefry((0,42),(0,e)); u = bitcast((bits>>9)|0x3F800000)-1, clip, g=-log(-log(u)).
// VALIDATED bit-exact vs reference (Rounds 2,4) — do not modify.
__device__ __forceinline__ float gumbel_from_e(uint32_t e){
  uint32_t x0 = 0u, x1 = e;
  const uint32_t ks0 = 0u, ks1 = 42u, ks2 = 0x1BD11BF0u;
  x0 += ks0; x1 += ks1;
#define TFR4(a,b,c,d2) \
  x0 += x1; x1 = rotl32(x1,(a)); x1 ^= x0; \
  x0 += x1; x1 = rotl32(x1,(b)); x1 ^= x0; \
  x0 += x1; x1 = rotl32(x1,(c)); x1 ^= x0; \
  x0 += x1; x1 = rotl32(x1,(d2)); x1 ^= x0;
  TFR4(13,15,26,6)  x0 += ks1; x1 += ks2 + 1u;
  TFR4(17,29,16,24) x0 += ks2; x1 += ks0 + 2u;
  TFR4(13,15,26,6)  x0 += ks0; x1 += ks1 + 3u;
  TFR4(17,29,16,24) x0 += ks1; x1 += ks2 + 4u;
  TFR4(13,15,26,6)  x0 += ks2; x1 += ks0 + 5u;
#undef TFR4
  uint32_t bits = x0 ^ x1;
  float u = __uint_as_float((bits >> 9) | 0x3F800000u) - 1.0f;
  u = fminf(fmaxf(u, 1.1920929e-07f), __uint_as_float(0x3F7FFFFEu));
  return -logf(-logf(u));
}

// Kernel 1 (Round-2 proven structure + fused zero-fill of own output slice):
// grid 4096 = m(4) x rowtile(64) x ktile(16); block 512 thr, 32 rows x 256 k.
// Writes logits, argmax partials into sample[row][0:64], and zero-fills
// sample/onehot for its rows x its k-slice (kt==0 skips sample[:,0:64]).
__global__ __launch_bounds__(512) void k_logits(
    const float* __restrict__ x, const float* __restrict__ cb,
    const float* __restrict__ temp, float* __restrict__ logit_out,
    float* __restrict__ sample, float* __restrict__ onehot){
  __shared__ float xl[32][36];     // 32 rows x 32 d, pad to 36
  __shared__ float cl[9216];       // 256 k x 32 d, stride 36 (conflict-free b128)
  __shared__ float c2l[256];
  __shared__ float x2l[32];

  const int tid = threadIdx.x;
  const int b = blockIdx.x;
  const int kt = b & 15;           // k-tile 0..15
  const int rt = (b >> 4) & 63;    // row-tile 0..63 (within m)
  const int m  = b >> 10;          // 0..3
  const int n  = rt >> 3;
  const int hw0 = (rt & 7) << 5;
  const int k0 = kt << 8;
  const int rowbase = ((n << 2) + m) * 256 + hw0;

  // ---- stage x tile (32 rows x 32 d) ----
  const float* xm = x + ((n * 128 + m * 32) * 256 + hw0);
  #pragma unroll
  for (int i = 0; i < 2; ++i){
    int idx = tid + (i << 9);
    int d = idx >> 5, r = idx & 31;
    xl[r][d] = xm[(d << 8) + r];
  }
  // ---- stage codebook tile (256 k x 32 d) as float4 ----
  const float4* cb4 = (const float4*)(cb + (m * 131072 + k0 * 32));
  #pragma unroll
  for (int i = 0; i < 4; ++i){
    int f = tid + (i << 9);
    float4 v = cb4[f];
    int kk = f >> 3, dq = f & 7;
    *(float4*)&cl[kk * 36 + (dq << 2)] = v;
  }
  __syncthreads();

  // ---- squared norms ----
  if (tid < 256){
    float s = 0.f;
    #pragma unroll
    for (int d = 0; d < 32; ++d){ float c = cl[tid*36 + d]; s = fmaf(c, c, s); }
    c2l[tid] = s;
  }
  if (tid < 32){
    float s = 0.f;
    #pragma unroll
    for (int d = 0; d < 32; ++d){ float v = xl[tid][d]; s = fmaf(v, v, s); }
    x2l[tid] = s;
  }
  __syncthreads();

  // ---- GEMM: each thread 4 rows x 4 ks ----
  const int kg = tid & 63;         // k-group 0..63, ks = kg + 64*j
  const int rg = tid >> 6;         // row-group 0..7 (uniform per wave)
  float acc[4][4];
  #pragma unroll
  for (int i = 0; i < 4; ++i)
    #pragma unroll
    for (int j = 0; j < 4; ++j) acc[i][j] = 0.f;

  #pragma unroll
  for (int dblk = 0; dblk < 8; ++dblk){
    float4 xa[4];
    #pragma unroll
    for (int i = 0; i < 4; ++i)
      xa[i] = *(const float4*)&xl[(rg << 2) + i][dblk << 2];
    #pragma unroll
    for (int j = 0; j < 4; ++j){
      float4 cv = *(const float4*)&cl[(kg + (j << 6)) * 36 + (dblk << 2)];
      #pragma unroll
      for (int i = 0; i < 4; ++i){
        acc[i][j] = fmaf(xa[i].x, cv.x, acc[i][j]);
        acc[i][j] = fmaf(xa[i].y, cv.y, acc[i][j]);
        acc[i][j] = fmaf(xa[i].z, cv.z, acc[i][j]);
        acc[i][j] = fmaf(xa[i].w, cv.w, acc[i][j]);
      }
    }
  }

  // ---- logits + gumbel + per-thread argmax (k ascending -> first-occurrence) ----
  const float tcl = fmaxf(temp[m], 1e-6f);
  float bl[4], bg[4]; int bli[4], bgi[4];
  #pragma unroll
  for (int i = 0; i < 4; ++i){ bl[i] = -INFINITY; bg[i] = -INFINITY; bli[i] = 0; bgi[i] = 0; }

  #pragma unroll
  for (int j = 0; j < 4; ++j){
    const int kk = kg + (j << 6);
    const int k_g = k0 + kk;
    const float c2 = c2l[kk];
    #pragma unroll
    for (int i = 0; i < 4; ++i){
      const int r = (rg << 2) + i;
      const int row_g = rowbase + r;
      float dist = x2l[r] + c2 - 2.0f * acc[i][j];
      float l = (-dist) * 0.015625f * tcl;          // (-dist/64)*t, /64 exact
      logit_out[((size_t)row_g << 12) + k_g] = l;
      float lg = l + gumbel_from_e(((uint32_t)row_g << 12) + (uint32_t)k_g);
      if (l  > bl[i]) { bl[i] = l;  bli[i] = k_g; }
      if (lg > bg[i]) { bg[i] = lg; bgi[i] = k_g; }
    }
  }

  // ---- block reduction over 64 k-groups (reuse cl as scratch) ----
  __syncthreads();                 // all cl reads done
  float* red = cl;                 // 4 arrays of 32*65 floats (pad 65)
  #pragma unroll
  for (int i = 0; i < 4; ++i){
    int r = (rg << 2) + i;
    red[        r * 65 + kg] = bl[i];
    red[2080 +  r * 65 + kg] = __int_as_float(bli[i]);
    red[4160 +  r * 65 + kg] = bg[i];
    red[6240 +  r * 65 + kg] = __int_as_float(bgi[i]);
  }
  __syncthreads();
  if (tid < 64){
    const int r = tid & 31;
    const bool doG = (tid >= 32);
    const int off_v = doG ? 4160 : 0;
    const int off_i = doG ? 6240 : 2080;
    float bv = -INFINITY; int bi = 0;
    for (int g2 = 0; g2 < 64; ++g2){
      float v = red[off_v + r * 65 + g2];
      int  ix = __float_as_int(red[off_i + r * 65 + g2]);
      if (v > bv || (v == bv && ix < bi)){ bv = v; bi = ix; }
    }
    const int row_g = rowbase + r;
    float* part = sample + ((size_t)row_g << 12);
    part[(doG ? 32 : 0)  + kt] = bv;
    part[(doG ? 48 : 16) + kt] = __int_as_float(bi);
  }

  // ---- fused zero-fill of this block's slice (end: fire-and-forget stores
  // drain while the next queued block computes; nothing waits on them) ----
  const float4 z4 = make_float4(0.f, 0.f, 0.f, 0.f);
  #pragma unroll
  for (int i2 = 0; i2 < 4; ++i2){
    int s = tid + (i2 << 9);            // 2048 float4 slots: 32 rows x 64
    int r = s >> 6, w4 = s & 63;
    size_t f4 = (((size_t)(rowbase + r)) << 10) + (k0 >> 2) + w4;
    ((float4*)onehot)[f4] = z4;
    if (!(kt == 0 && w4 < 16))          // keep sample[row][0:64] = partials
      ((float4*)sample)[f4] = z4;
  }
}

// Kernel 2: one wave per row (2048 blocks x 256 = 4 rows/block). Shuffle-reduce
// the 16 partials, zero sample[row][0:64], scatter the two 1.0s + code.
__global__ __launch_bounds__(256) void k_finalize(
    float* __restrict__ sample, float* __restrict__ code_out,
    float* __restrict__ onehot){
  const int tid = threadIdx.x;
  const int row = (blockIdx.x << 2) + (tid >> 6);
  const int lane = tid & 63;
  float* srow = sample + ((size_t)row << 12);
  float* orow = onehot + ((size_t)row << 12);

  // lanes 0-15 reduce L (logit argmax), lanes 16-31 reduce G (logit+gumbel)
  const int g = (lane >> 4) & 1;
  const int l16 = lane & 15;
  float v; int ix;
  if (lane < 32){
    v  = srow[g * 32 + l16];
    ix = __float_as_int(srow[g * 32 + 16 + l16]);
  } else { v = -INFINITY; ix = 0x7fffffff; }
  #pragma unroll
  for (int off = 1; off < 16; off <<= 1){
    float ov = __shfl_xor(v, off, 16);
    int   oi = __shfl_xor(ix, off, 16);
    if (ov > v || (ov == v && oi < ix)){ v = ov; ix = oi; }
  }
  const int codei = __shfl(ix, 0, 64);   // L winner
  const int hard  = __shfl(ix, 16, 64);  // G winner

  // zero sample[row][0:64]; owner lane embeds the 1.0 if hard < 64 (no race)
  if (lane < 16){
    float4 vs = make_float4(0.f, 0.f, 0.f, 0.f);
    if ((hard >> 2) == lane) ((float*)&vs)[hard & 3] = 1.0f;
    ((float4*)srow)[lane] = vs;
  } else if (lane == 16){
    if (hard >= 64) srow[hard] = 1.0f;   // region already zeroed by K1
  } else if (lane == 17){
    orow[codei] = 1.0f;                  // one_hot(argmax(logit)); zeroed by K1
  } else if (lane == 18){
    code_out[row] = (float)codei;
  }
}

extern "C" void kernel_launch(void* const* d_in, const int* in_sizes, int n_in,
                              void* d_out, int out_size, void* d_ws, size_t ws_size,
                              hipStream_t stream) {
  const float* x    = (const float*)d_in[0];
  const float* cb   = (const float*)d_in[1];
  const float* temp = (const float*)d_in[2];
  float* out    = (float*)d_out;
  float* sample = out;                       // 33554432
  float* code   = out + 33554432;            // 8192
  float* onehot = code + 8192;               // 33554432
  float* logit  = onehot + 33554432;         // 33554432

  hipLaunchKernelGGL(k_logits, dim3(4096), dim3(512), 0, stream,
                     x, cb, temp, logit, sample, onehot);
  hipLaunchKernelGGL(k_finalize, dim3(2048), dim3(256), 0, stream,
                     sample, code, onehot);
}